// Round 2
// baseline (849.207 us; speedup 1.0000x reference)
//
#include <hip/hip_runtime.h>
#include <stdint.h>

#define BB 64
#define SS 512
#define HIDD 40
#define HEADSN 4
#define DHH 10
#define DPP 12   // padded head dim (48B rows -> float4 aligned)
#define INTERN 20
#define EPSF 1e-5f

// ---------------- K1: LN1 + QKV projection ----------------
// grid 512 x 256. Block handles 64 rows. lane = local row, wave = j-part.
// Outputs q,k,v in [B, H, S, DPP] fp32 with pads zeroed.
__global__ __launch_bounds__(256) void k_ln_qkv(
    const float* __restrict__ x, const float* __restrict__ g, const float* __restrict__ be,
    const float* __restrict__ Wq, const float* __restrict__ bq,
    const float* __restrict__ Wk, const float* __restrict__ bk,
    const float* __restrict__ Wv, const float* __restrict__ bv,
    float* __restrict__ qo, float* __restrict__ ko, float* __restrict__ vo)
{
    __shared__ float sWT[40][128];   // [i][j], j = 0..119 valid (q|k|v concat), 120..127 zero
    __shared__ float sBias[128];
    __shared__ float sG[40], sBt[40];

    const int tid = threadIdx.x;
    for (int idx = tid; idx < 5120; idx += 256) {
        int i = idx >> 7, j = idx & 127;
        float val = 0.f;
        if (j < 40)       val = Wq[i * 40 + j];
        else if (j < 80)  val = Wk[i * 40 + (j - 40)];
        else if (j < 120) val = Wv[i * 40 + (j - 80)];
        sWT[i][j] = val;
    }
    if (tid < 128) {
        int j = tid;
        float val = 0.f;
        if (j < 40)       val = bq[j];
        else if (j < 80)  val = bk[j - 40];
        else if (j < 120) val = bv[j - 80];
        sBias[j] = val;
    }
    if (tid < 40) { sG[tid] = g[tid]; sBt[tid] = be[tid]; }
    __syncthreads();

    const int lane = tid & 63;
    const int part = tid >> 6;       // 0..3, each covers 32 of 128 padded outputs
    const int row  = blockIdx.x * 64 + lane;

    // load x row: 40 fp32 = 10 x float4 (row*160B, 16B aligned)
    float h[40];
    const float4* xp = (const float4*)(x + (size_t)row * 40);
#pragma unroll
    for (int c = 0; c < 10; c++) {
        float4 u = xp[c];
        h[c * 4 + 0] = u.x; h[c * 4 + 1] = u.y; h[c * 4 + 2] = u.z; h[c * 4 + 3] = u.w;
    }
    float mu = 0.f;
#pragma unroll
    for (int i = 0; i < 40; i++) mu += h[i];
    mu *= (1.0f / 40.0f);
    float var = 0.f;
#pragma unroll
    for (int i = 0; i < 40; i++) { float d = h[i] - mu; var += d * d; }
    var *= (1.0f / 40.0f);
    const float rs = rsqrtf(var + EPSF);
#pragma unroll
    for (int i = 0; i < 40; i++) h[i] = (h[i] - mu) * rs * sG[i] + sBt[i];

    const int j0 = part * 32;
    float acc[32];
#pragma unroll
    for (int jj = 0; jj < 32; jj++) acc[jj] = sBias[j0 + jj];
#pragma unroll
    for (int i = 0; i < 40; i++) {
        const float hi = h[i];
        const float4* wrow = (const float4*)&sWT[i][j0];
#pragma unroll
        for (int c = 0; c < 8; c++) {
            float4 wv = wrow[c];
            acc[c * 4 + 0] += hi * wv.x;
            acc[c * 4 + 1] += hi * wv.y;
            acc[c * 4 + 2] += hi * wv.z;
            acc[c * 4 + 3] += hi * wv.w;
        }
    }

    const int b = row >> 9, s = row & 511;
    float* outs[3] = {qo, ko, vo};
#pragma unroll
    for (int jj = 0; jj < 32; jj++) {
        int j = j0 + jj;
        if (j < 120) {
            int which = j / 40, r = j % 40, head = r / 10, d = r % 10;
            outs[which][((size_t)((b * 4 + head) * 512 + s)) * DPP + d] = acc[jj];
        }
    }
    if (part == 0) {
#pragma unroll
        for (int which = 0; which < 3; which++)
#pragma unroll
            for (int head = 0; head < 4; head++) {
                size_t base = ((size_t)((b * 4 + head) * 512 + s)) * DPP;
                outs[which][base + 10] = 0.f;
                outs[which][base + 11] = 0.f;
            }
    }
}

// ---------------- K2: attention (online softmax) ----------------
// grid 512 (bh x q-half), block 256, one query per thread.
__global__ __launch_bounds__(256) void k_attn(
    const float* __restrict__ qg, const float* __restrict__ kg,
    const float* __restrict__ vg, float* __restrict__ ctx)
{
    __shared__ float4 sK[512 * 3];
    __shared__ float4 sV[512 * 3];
    const int tid = threadIdx.x;
    const int bh = blockIdx.x >> 1;
    const int qt = blockIdx.x & 1;

    const float4* kp = (const float4*)(kg + (size_t)bh * 512 * DPP);
    const float4* vp = (const float4*)(vg + (size_t)bh * 512 * DPP);
    for (int idx = tid; idx < 1536; idx += 256) { sK[idx] = kp[idx]; sV[idx] = vp[idx]; }
    __syncthreads();

    const int qi = qt * 256 + tid;
    const float4* qp = (const float4*)(qg + ((size_t)bh * 512 + qi) * DPP);
    const float cscale = 1.4426950408889634f / 3.1622776601683795f;  // log2(e)/sqrt(DH)
    float4 q0 = qp[0], q1 = qp[1], q2 = qp[2];
    q0.x *= cscale; q0.y *= cscale; q0.z *= cscale; q0.w *= cscale;
    q1.x *= cscale; q1.y *= cscale; q1.z *= cscale; q1.w *= cscale;
    q2.x *= cscale; q2.y *= cscale; q2.z *= cscale; q2.w *= cscale;

    float m = -1e30f, l = 0.f;
    float4 a0 = {0, 0, 0, 0}, a1 = {0, 0, 0, 0}, a2 = {0, 0, 0, 0};

    for (int ks = 0; ks < 512; ks++) {
        float4 k0 = sK[ks * 3 + 0], k1 = sK[ks * 3 + 1], k2 = sK[ks * 3 + 2];
        float s = q0.x * k0.x + q0.y * k0.y + q0.z * k0.z + q0.w * k0.w
                + q1.x * k1.x + q1.y * k1.y + q1.z * k1.z + q1.w * k1.w
                + q2.x * k2.x + q2.y * k2.y + q2.z * k2.z + q2.w * k2.w;
        if (s > m) {
            float alpha = exp2f(m - s);
            m = s;
            l *= alpha;
            a0.x *= alpha; a0.y *= alpha; a0.z *= alpha; a0.w *= alpha;
            a1.x *= alpha; a1.y *= alpha; a1.z *= alpha; a1.w *= alpha;
            a2.x *= alpha; a2.y *= alpha;
        }
        float p = exp2f(s - m);
        l += p;
        float4 v0 = sV[ks * 3 + 0], v1 = sV[ks * 3 + 1], v2 = sV[ks * 3 + 2];
        a0.x += p * v0.x; a0.y += p * v0.y; a0.z += p * v0.z; a0.w += p * v0.w;
        a1.x += p * v1.x; a1.y += p * v1.y; a1.z += p * v1.z; a1.w += p * v1.w;
        a2.x += p * v2.x; a2.y += p * v2.y;  // a2.z/.w are pads, skip
    }
    const float inv = 1.f / l;
    const int b = bh >> 2, hh = bh & 3;
    float* op = ctx + ((size_t)(b * 512 + qi)) * 40 + hh * 10;
    op[0] = a0.x * inv; op[1] = a0.y * inv; op[2] = a0.z * inv; op[3] = a0.w * inv;
    op[4] = a1.x * inv; op[5] = a1.y * inv; op[6] = a1.z * inv; op[7] = a1.w * inv;
    op[8] = a2.x * inv; op[9] = a2.y * inv;
}

// ---------------- K3: Wo + residual + LN2 + FFN + residual ----------------
// grid 128 x 256, one row per thread.
__global__ __launch_bounds__(256) void k_out_ffn(
    const float* __restrict__ ctx, const float* __restrict__ x,
    const float* __restrict__ Wo, const float* __restrict__ bo,
    const float* __restrict__ g2, const float* __restrict__ bt2,
    const float* __restrict__ W1, const float* __restrict__ b1,
    const float* __restrict__ W2, const float* __restrict__ b2,
    float* __restrict__ out)
{
    __shared__ float sWo[40][40];
    __shared__ float sW1[40][20];
    __shared__ float sW2[20][40];
    __shared__ float sBo[40], sG2[40], sBt2[40], sB1[20], sB2[40];

    const int tid = threadIdx.x;
    for (int idx = tid; idx < 1600; idx += 256) sWo[idx / 40][idx % 40] = Wo[idx];
    for (int idx = tid; idx < 800; idx += 256) {
        sW1[idx / 20][idx % 20] = W1[idx];
        sW2[idx / 40][idx % 40] = W2[idx];
    }
    if (tid < 40) { sBo[tid] = bo[tid]; sG2[tid] = g2[tid]; sBt2[tid] = bt2[tid]; sB2[tid] = b2[tid]; }
    if (tid < 20) sB1[tid] = b1[tid];
    __syncthreads();

    const int row = blockIdx.x * 256 + tid;

    float acc[40];
    {   // acc = bo + x (residual folded into bias init)
        const float4* xp = (const float4*)(x + (size_t)row * 40);
#pragma unroll
        for (int c = 0; c < 10; c++) {
            float4 u = xp[c];
            acc[c * 4 + 0] = sBo[c * 4 + 0] + u.x;
            acc[c * 4 + 1] = sBo[c * 4 + 1] + u.y;
            acc[c * 4 + 2] = sBo[c * 4 + 2] + u.z;
            acc[c * 4 + 3] = sBo[c * 4 + 3] + u.w;
        }
    }
    {   // acc += ctx @ Wo
        float c[40];
        const float4* cp = (const float4*)(ctx + (size_t)row * 40);
#pragma unroll
        for (int i = 0; i < 10; i++) {
            float4 v = cp[i];
            c[i * 4 + 0] = v.x; c[i * 4 + 1] = v.y; c[i * 4 + 2] = v.z; c[i * 4 + 3] = v.w;
        }
#pragma unroll
        for (int i = 0; i < 40; i++) {
            const float ci = c[i];
            const float4* wrow = (const float4*)&sWo[i][0];
#pragma unroll
            for (int cc = 0; cc < 10; cc++) {
                float4 wv = wrow[cc];
                acc[cc * 4 + 0] += ci * wv.x;
                acc[cc * 4 + 1] += ci * wv.y;
                acc[cc * 4 + 2] += ci * wv.z;
                acc[cc * 4 + 3] += ci * wv.w;
            }
        }
    }
    // LN2
    float mu = 0.f;
#pragma unroll
    for (int i = 0; i < 40; i++) mu += acc[i];
    mu *= (1.0f / 40.0f);
    float var = 0.f;
#pragma unroll
    for (int i = 0; i < 40; i++) { float d = acc[i] - mu; var += d * d; }
    var *= (1.0f / 40.0f);
    const float rs = rsqrtf(var + EPSF);
    float h2[40];
#pragma unroll
    for (int i = 0; i < 40; i++) h2[i] = (acc[i] - mu) * rs * sG2[i] + sBt2[i];

    // inter = gelu(h2 @ W1 + b1)
    float it[20];
#pragma unroll
    for (int j = 0; j < 20; j++) it[j] = sB1[j];
#pragma unroll
    for (int i = 0; i < 40; i++) {
        const float hi = h2[i];
        const float4* wrow = (const float4*)&sW1[i][0];
#pragma unroll
        for (int cc = 0; cc < 5; cc++) {
            float4 wv = wrow[cc];
            it[cc * 4 + 0] += hi * wv.x;
            it[cc * 4 + 1] += hi * wv.y;
            it[cc * 4 + 2] += hi * wv.z;
            it[cc * 4 + 3] += hi * wv.w;
        }
    }
#pragma unroll
    for (int j = 0; j < 20; j++)
        it[j] = 0.5f * it[j] * (1.0f + erff(it[j] * 0.70710678118654752f));

    // out = inter @ W2 + b2 + acc (residual)
#pragma unroll
    for (int j = 0; j < 40; j++) acc[j] += sB2[j];
#pragma unroll
    for (int i = 0; i < 20; i++) {
        const float ii = it[i];
        const float4* wrow = (const float4*)&sW2[i][0];
#pragma unroll
        for (int cc = 0; cc < 10; cc++) {
            float4 wv = wrow[cc];
            acc[cc * 4 + 0] += ii * wv.x;
            acc[cc * 4 + 1] += ii * wv.y;
            acc[cc * 4 + 2] += ii * wv.z;
            acc[cc * 4 + 3] += ii * wv.w;
        }
    }
    // store 10 x float4
    float4* op = (float4*)(out + (size_t)row * 40);
#pragma unroll
    for (int c = 0; c < 10; c++) {
        float4 u;
        u.x = acc[c * 4 + 0]; u.y = acc[c * 4 + 1];
        u.z = acc[c * 4 + 2]; u.w = acc[c * 4 + 3];
        op[c] = u;
    }
}

extern "C" void kernel_launch(void* const* d_in, const int* in_sizes, int n_in,
                              void* d_out, int out_size, void* d_ws, size_t ws_size,
                              hipStream_t stream)
{
    const float* x   = (const float*)d_in[0];
    const float* g1  = (const float*)d_in[1];
    const float* be1 = (const float*)d_in[2];
    const float* Wq  = (const float*)d_in[3];
    const float* bq  = (const float*)d_in[4];
    const float* Wk  = (const float*)d_in[5];
    const float* bk  = (const float*)d_in[6];
    const float* Wv  = (const float*)d_in[7];
    const float* bv  = (const float*)d_in[8];
    const float* Wo  = (const float*)d_in[9];
    const float* bo  = (const float*)d_in[10];
    const float* g2  = (const float*)d_in[11];
    const float* bt2 = (const float*)d_in[12];
    const float* W1  = (const float*)d_in[13];
    const float* b1  = (const float*)d_in[14];
    const float* W2  = (const float*)d_in[15];
    const float* b2  = (const float*)d_in[16];

    float* ws = (float*)d_ws;
    const size_t QKV = (size_t)BB * HEADSN * SS * DPP;  // 1,572,864 floats
    float* q   = ws;
    float* k   = ws + QKV;
    float* v   = ws + 2 * QKV;
    float* ctx = ws + 3 * QKV;  // B*S*40 floats

    k_ln_qkv<<<512, 256, 0, stream>>>(x, g1, be1, Wq, bq, Wk, bk, Wv, bv, q, k, v);
    k_attn<<<512, 256, 0, stream>>>(q, k, v, ctx);
    k_out_ffn<<<128, 256, 0, stream>>>(ctx, x, Wo, bo, g2, bt2, W1, b1, W2, b2,
                                       (float*)d_out);
}

// Round 3
// 269.951 us; speedup vs baseline: 3.1458x; 3.1458x over previous
//
#include <hip/hip_runtime.h>
#include <stdint.h>

#define BB 64
#define SS 512
#define DPP 12   // padded head dim (48B rows -> float4 aligned)
#define EPSF 1e-5f

// ---------------- K1: LN1 + QKV projection ----------------
// grid 512 x 256. Block handles 64 rows; wave=j-part (32 cols), lane=row.
// Outputs q,k,v in [B, H, S, DPP] fp32 with pads zeroed, via LDS staging
// so all global stores are coalesced float4.
__global__ __launch_bounds__(256) void k_ln_qkv(
    const float* __restrict__ x, const float* __restrict__ g, const float* __restrict__ be,
    const float* __restrict__ Wq, const float* __restrict__ bq,
    const float* __restrict__ Wk, const float* __restrict__ bk,
    const float* __restrict__ Wv, const float* __restrict__ bv,
    float* __restrict__ qo, float* __restrict__ ko, float* __restrict__ vo)
{
    __shared__ float sWT[40][128];   // [i][j], j=0..119 valid (q|k|v), 120..127 zero
    __shared__ float sBias[128];
    __shared__ float sG[40], sBt[40];
    __shared__ float sX[64][41];     // stride 41: lane-distinct banks on row reads
    __shared__ float sOut[64][129];  // stride 129: conflict-free flush reads

    const int tid = threadIdx.x;
    for (int idx = tid; idx < 5120; idx += 256) {
        int i = idx >> 7, j = idx & 127;
        float val = 0.f;
        if (j < 40)       val = Wq[i * 40 + j];
        else if (j < 80)  val = Wk[i * 40 + (j - 40)];
        else if (j < 120) val = Wv[i * 40 + (j - 80)];
        sWT[i][j] = val;
    }
    if (tid < 128) {
        int j = tid;
        float val = 0.f;
        if (j < 40)       val = bq[j];
        else if (j < 80)  val = bk[j - 40];
        else if (j < 120) val = bv[j - 80];
        sBias[j] = val;
    }
    if (tid < 40) { sG[tid] = g[tid]; sBt[tid] = be[tid]; }

    // coalesced stage of 64 x-rows (64*40 floats = 640 float4, contiguous)
    const float4* xblk = (const float4*)(x + (size_t)blockIdx.x * 64 * 40);
    for (int idx = tid; idx < 640; idx += 256) {
        float4 u = xblk[idx];
        int fl = idx * 4;
        int r = fl / 40, c = fl - r * 40;   // 40%4==0: float4 never crosses rows
        sX[r][c] = u.x; sX[r][c + 1] = u.y; sX[r][c + 2] = u.z; sX[r][c + 3] = u.w;
    }
    __syncthreads();

    const int lane = tid & 63;
    const int part = tid >> 6;       // wave id = j-part, 32 padded cols each

    float h[40];
#pragma unroll
    for (int i = 0; i < 40; i++) h[i] = sX[lane][i];

    float mu = 0.f;
#pragma unroll
    for (int i = 0; i < 40; i++) mu += h[i];
    mu *= (1.0f / 40.0f);
    float var = 0.f;
#pragma unroll
    for (int i = 0; i < 40; i++) { float d = h[i] - mu; var += d * d; }
    var *= (1.0f / 40.0f);
    const float rs = rsqrtf(var + EPSF);
#pragma unroll
    for (int i = 0; i < 40; i++) h[i] = (h[i] - mu) * rs * sG[i] + sBt[i];

    const int j0 = part * 32;
    float acc[32];
#pragma unroll
    for (int jj = 0; jj < 32; jj++) acc[jj] = sBias[j0 + jj];
#pragma unroll
    for (int i = 0; i < 40; i++) {
        const float hi = h[i];
        const float4* wrow = (const float4*)&sWT[i][j0];  // wave-uniform -> broadcast
#pragma unroll
        for (int c = 0; c < 8; c++) {
            float4 wv = wrow[c];
            acc[c * 4 + 0] += hi * wv.x;
            acc[c * 4 + 1] += hi * wv.y;
            acc[c * 4 + 2] += hi * wv.z;
            acc[c * 4 + 3] += hi * wv.w;
        }
    }
#pragma unroll
    for (int jj = 0; jj < 32; jj++) sOut[lane][j0 + jj] = acc[jj];
    __syncthreads();

    // coalesced flush: 12 regions (q/k/v x 4 heads), each 64 rows x 12 floats
    // contiguous in global = 192 float4. 2304 float4 total, 9 per thread.
    const int row0 = blockIdx.x * 64;
    const int b4 = (row0 >> 9) * 4, s0 = row0 & 511;
    for (int fi = tid; fi < 2304; fi += 256) {
        int region = fi / 192;
        int kk = fi - region * 192;
        int w = region >> 2, hh = region & 3;
        int r = kk / 3, gg = kk - r * 3;
        int bj = w * 40 + hh * 10 + gg * 4;
        float4 val;
        val.x = sOut[r][bj];
        val.y = sOut[r][bj + 1];
        val.z = (gg == 2) ? 0.f : sOut[r][bj + 2];
        val.w = (gg == 2) ? 0.f : sOut[r][bj + 3];
        float* op = (w == 0) ? qo : (w == 1) ? ko : vo;
        *(float4*)(op + ((size_t)((b4 + hh) * 512 + s0 + r)) * DPP + gg * 4) = val;
    }
}

// ---------------- K2: attention (tiled branchless online softmax) ----------------
// grid 512 (bh x q-half), block 256, one query per thread, 8-key tiles.
__global__ __launch_bounds__(256) void k_attn(
    const float* __restrict__ qg, const float* __restrict__ kg,
    const float* __restrict__ vg, float* __restrict__ ctx)
{
    __shared__ float4 sK[512 * 3];
    __shared__ float4 sV[512 * 3];
    const int tid = threadIdx.x;
    const int bh = blockIdx.x >> 1;
    const int qt = blockIdx.x & 1;

    const float4* kp = (const float4*)(kg + (size_t)bh * 512 * DPP);
    const float4* vp = (const float4*)(vg + (size_t)bh * 512 * DPP);
    for (int idx = tid; idx < 1536; idx += 256) { sK[idx] = kp[idx]; sV[idx] = vp[idx]; }
    __syncthreads();

    const int qi = qt * 256 + tid;
    const float4* qp = (const float4*)(qg + ((size_t)bh * 512 + qi) * DPP);
    const float cscale = 1.4426950408889634f / 3.1622776601683795f;  // log2(e)/sqrt(DH)
    float4 q0 = qp[0], q1 = qp[1], q2 = qp[2];
    q0.x *= cscale; q0.y *= cscale; q0.z *= cscale; q0.w *= cscale;
    q1.x *= cscale; q1.y *= cscale; q1.z *= cscale; q1.w *= cscale;
    q2.x *= cscale; q2.y *= cscale; q2.z *= cscale; q2.w *= cscale;

    float m = -1e30f, l = 0.f;
    float a[10];
#pragma unroll
    for (int d = 0; d < 10; d++) a[d] = 0.f;

    for (int kt = 0; kt < 512; kt += 8) {
        float sc[8];
#pragma unroll
        for (int u = 0; u < 8; u++) {
            const float4 k0 = sK[(kt + u) * 3 + 0];
            const float4 k1 = sK[(kt + u) * 3 + 1];
            const float4 k2 = sK[(kt + u) * 3 + 2];
            sc[u] = q0.x * k0.x + q0.y * k0.y + q0.z * k0.z + q0.w * k0.w
                  + q1.x * k1.x + q1.y * k1.y + q1.z * k1.z + q1.w * k1.w
                  + q2.x * k2.x + q2.y * k2.y + q2.z * k2.z + q2.w * k2.w;
        }
        float tm01 = fmaxf(sc[0], sc[1]), tm23 = fmaxf(sc[2], sc[3]);
        float tm45 = fmaxf(sc[4], sc[5]), tm67 = fmaxf(sc[6], sc[7]);
        float tmax = fmaxf(fmaxf(tm01, tm23), fmaxf(tm45, tm67));
        float newm = fmaxf(m, tmax);
        float alpha = exp2f(m - newm);   // m=-1e30 first tile -> alpha=0, no NaN
        m = newm;
        l *= alpha;
#pragma unroll
        for (int d = 0; d < 10; d++) a[d] *= alpha;
#pragma unroll
        for (int u = 0; u < 8; u++) {
            float p = exp2f(sc[u] - m);
            l += p;
            const float4 v0 = sV[(kt + u) * 3 + 0];
            const float4 v1 = sV[(kt + u) * 3 + 1];
            const float4 v2 = sV[(kt + u) * 3 + 2];
            a[0] += p * v0.x; a[1] += p * v0.y; a[2] += p * v0.z; a[3] += p * v0.w;
            a[4] += p * v1.x; a[5] += p * v1.y; a[6] += p * v1.z; a[7] += p * v1.w;
            a[8] += p * v2.x; a[9] += p * v2.y;
        }
    }
    const float inv = 1.f / l;
    const int b = bh >> 2, hh = bh & 3;
    float* op = ctx + ((size_t)(b * 512 + qi)) * 40 + hh * 10;
#pragma unroll
    for (int d = 0; d < 10; d++) op[d] = a[d] * inv;
}

// ---------------- K3: Wo + residual + LN2 + FFN + residual ----------------
// grid 256 x 128, one row per thread.
__global__ __launch_bounds__(128) void k_out_ffn(
    const float* __restrict__ ctx, const float* __restrict__ x,
    const float* __restrict__ Wo, const float* __restrict__ bo,
    const float* __restrict__ g2, const float* __restrict__ bt2,
    const float* __restrict__ W1, const float* __restrict__ b1,
    const float* __restrict__ W2, const float* __restrict__ b2,
    float* __restrict__ out)
{
    __shared__ float sWo[40][40];
    __shared__ float sW1[40][20];
    __shared__ float sW2[20][40];
    __shared__ float sBo[40], sG2[40], sBt2[40], sB1[20], sB2[40];

    const int tid = threadIdx.x;
    for (int idx = tid; idx < 1600; idx += 128) sWo[idx / 40][idx % 40] = Wo[idx];
    for (int idx = tid; idx < 800; idx += 128) {
        sW1[idx / 20][idx % 20] = W1[idx];
        sW2[idx / 40][idx % 40] = W2[idx];
    }
    if (tid < 40) { sBo[tid] = bo[tid]; sG2[tid] = g2[tid]; sBt2[tid] = bt2[tid]; sB2[tid] = b2[tid]; }
    if (tid < 20) sB1[tid] = b1[tid];
    __syncthreads();

    const int row = blockIdx.x * 128 + tid;

    float acc[40];
    {   // acc = bo + x (residual folded into bias init)
        const float4* xp = (const float4*)(x + (size_t)row * 40);
#pragma unroll
        for (int c = 0; c < 10; c++) {
            float4 u = xp[c];
            acc[c * 4 + 0] = sBo[c * 4 + 0] + u.x;
            acc[c * 4 + 1] = sBo[c * 4 + 1] + u.y;
            acc[c * 4 + 2] = sBo[c * 4 + 2] + u.z;
            acc[c * 4 + 3] = sBo[c * 4 + 3] + u.w;
        }
    }
    {   // acc += ctx @ Wo
        float c[40];
        const float4* cp = (const float4*)(ctx + (size_t)row * 40);
#pragma unroll
        for (int i = 0; i < 10; i++) {
            float4 v = cp[i];
            c[i * 4 + 0] = v.x; c[i * 4 + 1] = v.y; c[i * 4 + 2] = v.z; c[i * 4 + 3] = v.w;
        }
#pragma unroll
        for (int i = 0; i < 40; i++) {
            const float ci = c[i];
            const float4* wrow = (const float4*)&sWo[i][0];
#pragma unroll
            for (int cc = 0; cc < 10; cc++) {
                float4 wv = wrow[cc];
                acc[cc * 4 + 0] += ci * wv.x;
                acc[cc * 4 + 1] += ci * wv.y;
                acc[cc * 4 + 2] += ci * wv.z;
                acc[cc * 4 + 3] += ci * wv.w;
            }
        }
    }
    // LN2
    float mu = 0.f;
#pragma unroll
    for (int i = 0; i < 40; i++) mu += acc[i];
    mu *= (1.0f / 40.0f);
    float var = 0.f;
#pragma unroll
    for (int i = 0; i < 40; i++) { float d = acc[i] - mu; var += d * d; }
    var *= (1.0f / 40.0f);
    const float rs = rsqrtf(var + EPSF);
    float h2[40];
#pragma unroll
    for (int i = 0; i < 40; i++) h2[i] = (acc[i] - mu) * rs * sG2[i] + sBt2[i];

    // inter = gelu(h2 @ W1 + b1)
    float it[20];
#pragma unroll
    for (int j = 0; j < 20; j++) it[j] = sB1[j];
#pragma unroll
    for (int i = 0; i < 40; i++) {
        const float hi = h2[i];
        const float4* wrow = (const float4*)&sW1[i][0];
#pragma unroll
        for (int cc = 0; cc < 5; cc++) {
            float4 wv = wrow[cc];
            it[cc * 4 + 0] += hi * wv.x;
            it[cc * 4 + 1] += hi * wv.y;
            it[cc * 4 + 2] += hi * wv.z;
            it[cc * 4 + 3] += hi * wv.w;
        }
    }
#pragma unroll
    for (int j = 0; j < 20; j++)
        it[j] = 0.5f * it[j] * (1.0f + erff(it[j] * 0.70710678118654752f));

    // out = inter @ W2 + b2 + acc (residual)
#pragma unroll
    for (int j = 0; j < 40; j++) acc[j] += sB2[j];
#pragma unroll
    for (int i = 0; i < 20; i++) {
        const float ii = it[i];
        const float4* wrow = (const float4*)&sW2[i][0];
#pragma unroll
        for (int cc = 0; cc < 10; cc++) {
            float4 wv = wrow[cc];
            acc[cc * 4 + 0] += ii * wv.x;
            acc[cc * 4 + 1] += ii * wv.y;
            acc[cc * 4 + 2] += ii * wv.z;
            acc[cc * 4 + 3] += ii * wv.w;
        }
    }
    // store 10 x float4
    float4* op = (float4*)(out + (size_t)row * 40);
#pragma unroll
    for (int c = 0; c < 10; c++) {
        float4 u;
        u.x = acc[c * 4 + 0]; u.y = acc[c * 4 + 1];
        u.z = acc[c * 4 + 2]; u.w = acc[c * 4 + 3];
        op[c] = u;
    }
}

extern "C" void kernel_launch(void* const* d_in, const int* in_sizes, int n_in,
                              void* d_out, int out_size, void* d_ws, size_t ws_size,
                              hipStream_t stream)
{
    const float* x   = (const float*)d_in[0];
    const float* g1  = (const float*)d_in[1];
    const float* be1 = (const float*)d_in[2];
    const float* Wq  = (const float*)d_in[3];
    const float* bq  = (const float*)d_in[4];
    const float* Wk  = (const float*)d_in[5];
    const float* bk  = (const float*)d_in[6];
    const float* Wv  = (const float*)d_in[7];
    const float* bv  = (const float*)d_in[8];
    const float* Wo  = (const float*)d_in[9];
    const float* bo  = (const float*)d_in[10];
    const float* g2  = (const float*)d_in[11];
    const float* bt2 = (const float*)d_in[12];
    const float* W1  = (const float*)d_in[13];
    const float* b1  = (const float*)d_in[14];
    const float* W2  = (const float*)d_in[15];
    const float* b2  = (const float*)d_in[16];

    float* ws = (float*)d_ws;
    const size_t QKV = (size_t)BB * 4 * SS * DPP;  // 1,572,864 floats
    float* q   = ws;
    float* k   = ws + QKV;
    float* v   = ws + 2 * QKV;
    float* ctx = ws + 3 * QKV;  // B*S*40 floats

    k_ln_qkv<<<512, 256, 0, stream>>>(x, g1, be1, Wq, bq, Wk, bk, Wv, bv, q, k, v);
    k_attn<<<512, 256, 0, stream>>>(q, k, v, ctx);
    k_out_ffn<<<256, 128, 0, stream>>>(ctx, x, Wo, bo, g2, bt2, W1, b1, W2, b2,
                                       (float*)d_out);
}

// Round 4
// 202.579 us; speedup vs baseline: 4.1920x; 1.3326x over previous
//
#include <hip/hip_runtime.h>
#include <stdint.h>

#define BB 64
#define SS 512
#define DPP 12   // padded head dim (48B rows -> float4 aligned)
#define EPSF 1e-5f

// ---------------- K1: LN1 + QKV projection ----------------
// grid 512 x 256. Block = 64 rows; wave = j-part (32 cols), lane = row.
// Row state stays in LDS (no h[40] in registers -> no spills).
__global__ __launch_bounds__(256) void k_ln_qkv(
    const float* __restrict__ x, const float* __restrict__ g, const float* __restrict__ be,
    const float* __restrict__ Wq, const float* __restrict__ bq,
    const float* __restrict__ Wk, const float* __restrict__ bk,
    const float* __restrict__ Wv, const float* __restrict__ bv,
    float* __restrict__ qo, float* __restrict__ ko, float* __restrict__ vo)
{
    __shared__ float sWT[40][128];   // [i][j], j=0..119 valid (q|k|v), 120..127 zero
    __shared__ float sBias[128];
    __shared__ float sG[40], sBt[40];
    __shared__ float sX[64][41];     // stride 41: 2-way (free) on lane-row reads
    __shared__ float sOut[64][129];  // stride 129: conflict-free flush reads

    const int tid = threadIdx.x;
    for (int idx = tid; idx < 5120; idx += 256) {
        int i = idx >> 7, j = idx & 127;
        float val = 0.f;
        if (j < 40)       val = Wq[i * 40 + j];
        else if (j < 80)  val = Wk[i * 40 + (j - 40)];
        else if (j < 120) val = Wv[i * 40 + (j - 80)];
        sWT[i][j] = val;
    }
    if (tid < 128) {
        int j = tid;
        float val = 0.f;
        if (j < 40)       val = bq[j];
        else if (j < 80)  val = bk[j - 40];
        else if (j < 120) val = bv[j - 80];
        sBias[j] = val;
    }
    if (tid < 40) { sG[tid] = g[tid]; sBt[tid] = be[tid]; }

    // coalesced stage of 64 x-rows (640 float4, contiguous)
    const float4* xblk = (const float4*)(x + (size_t)blockIdx.x * 64 * 40);
    for (int idx = tid; idx < 640; idx += 256) {
        float4 u = xblk[idx];
        int fl = idx * 4;
        int r = fl / 40, c = fl - r * 40;   // 40%4==0: float4 never crosses rows
        sX[r][c] = u.x; sX[r][c + 1] = u.y; sX[r][c + 2] = u.z; sX[r][c + 3] = u.w;
    }
    __syncthreads();

    const int lane = tid & 63;       // row
    const int part = tid >> 6;       // wave id = j-part (32 padded cols)
    const int j0 = part * 32;

    // LN stats from LDS (two-pass, redundant across the 4 waves)
    float sum = 0.f;
#pragma unroll 8
    for (int i = 0; i < 40; i++) sum += sX[lane][i];
    const float mu = sum * 0.025f;
    float var = 0.f;
#pragma unroll 8
    for (int i = 0; i < 40; i++) { float d = sX[lane][i] - mu; var += d * d; }
    const float rs = rsqrtf(var * 0.025f + EPSF);

    float acc[32];
#pragma unroll
    for (int jj = 0; jj < 32; jj++) acc[jj] = sBias[j0 + jj];
#pragma unroll 4
    for (int i = 0; i < 40; i++) {
        const float hi = (sX[lane][i] - mu) * rs * sG[i] + sBt[i];
        const float4* wrow = (const float4*)&sWT[i][j0];  // wave-uniform -> broadcast
#pragma unroll
        for (int c = 0; c < 8; c++) {
            float4 wv = wrow[c];
            acc[c * 4 + 0] += hi * wv.x;
            acc[c * 4 + 1] += hi * wv.y;
            acc[c * 4 + 2] += hi * wv.z;
            acc[c * 4 + 3] += hi * wv.w;
        }
    }
#pragma unroll
    for (int jj = 0; jj < 32; jj++) sOut[lane][j0 + jj] = acc[jj];
    __syncthreads();

    // coalesced flush: 12 regions (q/k/v x 4 heads), each 64 rows x 12 floats
    const int row0 = blockIdx.x * 64;
    const int b4 = (row0 >> 9) * 4, s0 = row0 & 511;
    for (int fi = tid; fi < 2304; fi += 256) {
        int region = fi / 192;
        int kk = fi - region * 192;
        int w = region >> 2, hh = region & 3;
        int r = kk / 3, gg = kk - r * 3;
        int bj = w * 40 + hh * 10 + gg * 4;
        float4 val;
        val.x = sOut[r][bj];
        val.y = sOut[r][bj + 1];
        val.z = (gg == 2) ? 0.f : sOut[r][bj + 2];
        val.w = (gg == 2) ? 0.f : sOut[r][bj + 3];
        float* op = (w == 0) ? qo : (w == 1) ? ko : vo;
        *(float4*)(op + ((size_t)((b4 + hh) * 512 + s0 + r)) * DPP + gg * 4) = val;
    }
}

// ---------------- K2: attention (tiled branchless online softmax) ----------------
// grid 512 (bh x q-half), block 256, one query per thread, 8-key tiles.
__global__ __launch_bounds__(256) void k_attn(
    const float* __restrict__ qg, const float* __restrict__ kg,
    const float* __restrict__ vg, float* __restrict__ ctx)
{
    __shared__ float4 sK[512 * 3];
    __shared__ float4 sV[512 * 3];
    const int tid = threadIdx.x;
    const int bh = blockIdx.x >> 1;
    const int qt = blockIdx.x & 1;

    const float4* kp = (const float4*)(kg + (size_t)bh * 512 * DPP);
    const float4* vp = (const float4*)(vg + (size_t)bh * 512 * DPP);
    for (int idx = tid; idx < 1536; idx += 256) { sK[idx] = kp[idx]; sV[idx] = vp[idx]; }
    __syncthreads();

    const int qi = qt * 256 + tid;
    const float4* qp = (const float4*)(qg + ((size_t)bh * 512 + qi) * DPP);
    const float cscale = 1.4426950408889634f / 3.1622776601683795f;  // log2(e)/sqrt(DH)
    float4 q0 = qp[0], q1 = qp[1], q2 = qp[2];
    q0.x *= cscale; q0.y *= cscale; q0.z *= cscale; q0.w *= cscale;
    q1.x *= cscale; q1.y *= cscale; q1.z *= cscale; q1.w *= cscale;
    q2.x *= cscale; q2.y *= cscale; q2.z *= cscale; q2.w *= cscale;

    float m = -1e30f, l = 0.f;
    float a[10];
#pragma unroll
    for (int d = 0; d < 10; d++) a[d] = 0.f;

    for (int kt = 0; kt < 512; kt += 8) {
        float sc[8];
#pragma unroll
        for (int u = 0; u < 8; u++) {
            const float4 k0 = sK[(kt + u) * 3 + 0];
            const float4 k1 = sK[(kt + u) * 3 + 1];
            const float4 k2 = sK[(kt + u) * 3 + 2];
            sc[u] = q0.x * k0.x + q0.y * k0.y + q0.z * k0.z + q0.w * k0.w
                  + q1.x * k1.x + q1.y * k1.y + q1.z * k1.z + q1.w * k1.w
                  + q2.x * k2.x + q2.y * k2.y + q2.z * k2.z + q2.w * k2.w;
        }
        float tm01 = fmaxf(sc[0], sc[1]), tm23 = fmaxf(sc[2], sc[3]);
        float tm45 = fmaxf(sc[4], sc[5]), tm67 = fmaxf(sc[6], sc[7]);
        float tmax = fmaxf(fmaxf(tm01, tm23), fmaxf(tm45, tm67));
        float newm = fmaxf(m, tmax);
        float alpha = exp2f(m - newm);   // m=-1e30 first tile -> alpha=0, no NaN
        m = newm;
        l *= alpha;
#pragma unroll
        for (int d = 0; d < 10; d++) a[d] *= alpha;
#pragma unroll
        for (int u = 0; u < 8; u++) {
            float p = exp2f(sc[u] - m);
            l += p;
            const float4 v0 = sV[(kt + u) * 3 + 0];
            const float4 v1 = sV[(kt + u) * 3 + 1];
            const float4 v2 = sV[(kt + u) * 3 + 2];
            a[0] += p * v0.x; a[1] += p * v0.y; a[2] += p * v0.z; a[3] += p * v0.w;
            a[4] += p * v1.x; a[5] += p * v1.y; a[6] += p * v1.z; a[7] += p * v1.w;
            a[8] += p * v2.x; a[9] += p * v2.y;
        }
    }
    const float inv = 1.f / l;
    const int b = bh >> 2, hh = bh & 3;
    float* op = ctx + ((size_t)(b * 512 + qi)) * 40 + hh * 10;
#pragma unroll
    for (int d = 0; d < 10; d++) op[d] = a[d] * inv;
}

// ---------------- K3: Wo + residual + LN2 + FFN + residual ----------------
// grid 512 x 256. Block = 64 rows; wave = j-part (10 cols), lane = row.
// All row state through LDS; per-thread registers ~acc[10] -> no spills.
__global__ __launch_bounds__(256) void k_out_ffn(
    const float* __restrict__ ctx, const float* __restrict__ x,
    const float* __restrict__ Wo, const float* __restrict__ bo,
    const float* __restrict__ g2, const float* __restrict__ bt2,
    const float* __restrict__ W1, const float* __restrict__ b1,
    const float* __restrict__ W2, const float* __restrict__ b2,
    float* __restrict__ out)
{
    __shared__ float sWo[40][40];
    __shared__ float sW1[40][20];
    __shared__ float sW2[20][40];
    __shared__ float sBo[40], sG2[40], sBt2[40], sB1[20], sB2[40];
    __shared__ float sCtx[64][41];   // ctx rows; reused as out staging
    __shared__ float sAtt[64][41];   // attn_out rows (pre-LN2, residual source)
    __shared__ float sH[64][41];     // x rows first, then h2 rows
    __shared__ float sIt[64][21];    // gelu(FFN1) rows

    const int tid = threadIdx.x;
    for (int idx = tid; idx < 1600; idx += 256) sWo[idx / 40][idx % 40] = Wo[idx];
    for (int idx = tid; idx < 800; idx += 256) {
        sW1[idx / 20][idx % 20] = W1[idx];
        sW2[idx / 40][idx % 40] = W2[idx];
    }
    if (tid < 40) { sBo[tid] = bo[tid]; sG2[tid] = g2[tid]; sBt2[tid] = bt2[tid]; sB2[tid] = b2[tid]; }
    if (tid < 20) sB1[tid] = b1[tid];

    // coalesced stage of ctx and x rows (640 float4 each)
    const float4* cblk = (const float4*)(ctx + (size_t)blockIdx.x * 64 * 40);
    const float4* xblk = (const float4*)(x + (size_t)blockIdx.x * 64 * 40);
    for (int idx = tid; idx < 640; idx += 256) {
        int fl = idx * 4;
        int r = fl / 40, c = fl - r * 40;
        float4 u = cblk[idx];
        sCtx[r][c] = u.x; sCtx[r][c + 1] = u.y; sCtx[r][c + 2] = u.z; sCtx[r][c + 3] = u.w;
        float4 w = xblk[idx];
        sH[r][c] = w.x; sH[r][c + 1] = w.y; sH[r][c + 2] = w.z; sH[r][c + 3] = w.w;
    }
    __syncthreads();

    const int lane = tid & 63;   // row
    const int wv = tid >> 6;     // 0..3
    const int j0 = wv * 10;

    // attn_out cols j0..j0+9: bo + x + ctx@Wo
    float acc[10];
#pragma unroll
    for (int j = 0; j < 10; j++) acc[j] = sBo[j0 + j] + sH[lane][j0 + j];
#pragma unroll 8
    for (int i = 0; i < 40; i++) {
        const float ci = sCtx[lane][i];
#pragma unroll
        for (int j = 0; j < 10; j++) acc[j] += ci * sWo[i][j0 + j];
    }
#pragma unroll
    for (int j = 0; j < 10; j++) sAtt[lane][j0 + j] = acc[j];
    __syncthreads();

    // LN2 stats (two-pass, redundant across waves)
    float sum = 0.f;
#pragma unroll 8
    for (int i = 0; i < 40; i++) sum += sAtt[lane][i];
    const float mu = sum * 0.025f;
    float var = 0.f;
#pragma unroll 8
    for (int i = 0; i < 40; i++) { float d = sAtt[lane][i] - mu; var += d * d; }
    const float rs = rsqrtf(var * 0.025f + EPSF);
#pragma unroll
    for (int j = 0; j < 10; j++)
        sH[lane][j0 + j] = (acc[j] - mu) * rs * sG2[j0 + j] + sBt2[j0 + j];
    __syncthreads();

    // FFN1 + gelu: wave computes 5 of 20 inter cols
    const int f0 = wv * 5;
    float it[5];
#pragma unroll
    for (int j = 0; j < 5; j++) it[j] = sB1[f0 + j];
#pragma unroll 8
    for (int i = 0; i < 40; i++) {
        const float hi = sH[lane][i];
#pragma unroll
        for (int j = 0; j < 5; j++) it[j] += hi * sW1[i][f0 + j];
    }
#pragma unroll
    for (int j = 0; j < 5; j++) {
        float t = it[j];
        sIt[lane][f0 + j] = 0.5f * t * (1.0f + erff(t * 0.70710678118654752f));
    }
    __syncthreads();

    // FFN2 + residual: wave computes 10 of 40 out cols
    float o[10];
#pragma unroll
    for (int j = 0; j < 10; j++) o[j] = acc[j] + sB2[j0 + j];
#pragma unroll 4
    for (int i = 0; i < 20; i++) {
        const float ii = sIt[lane][i];
#pragma unroll
        for (int j = 0; j < 10; j++) o[j] += ii * sW2[i][j0 + j];
    }
#pragma unroll
    for (int j = 0; j < 10; j++) sCtx[lane][j0 + j] = o[j];  // reuse as out staging
    __syncthreads();

    // coalesced flush
    float4* oblk = (float4*)(out + (size_t)blockIdx.x * 64 * 40);
    for (int idx = tid; idx < 640; idx += 256) {
        int fl = idx * 4;
        int r = fl / 40, c = fl - r * 40;
        float4 u;
        u.x = sCtx[r][c]; u.y = sCtx[r][c + 1]; u.z = sCtx[r][c + 2]; u.w = sCtx[r][c + 3];
        oblk[idx] = u;
    }
}

extern "C" void kernel_launch(void* const* d_in, const int* in_sizes, int n_in,
                              void* d_out, int out_size, void* d_ws, size_t ws_size,
                              hipStream_t stream)
{
    const float* x   = (const float*)d_in[0];
    const float* g1  = (const float*)d_in[1];
    const float* be1 = (const float*)d_in[2];
    const float* Wq  = (const float*)d_in[3];
    const float* bq  = (const float*)d_in[4];
    const float* Wk  = (const float*)d_in[5];
    const float* bk  = (const float*)d_in[6];
    const float* Wv  = (const float*)d_in[7];
    const float* bv  = (const float*)d_in[8];
    const float* Wo  = (const float*)d_in[9];
    const float* bo  = (const float*)d_in[10];
    const float* g2  = (const float*)d_in[11];
    const float* bt2 = (const float*)d_in[12];
    const float* W1  = (const float*)d_in[13];
    const float* b1  = (const float*)d_in[14];
    const float* W2  = (const float*)d_in[15];
    const float* b2  = (const float*)d_in[16];

    float* ws = (float*)d_ws;
    const size_t QKV = (size_t)BB * 4 * SS * DPP;  // 1,572,864 floats
    float* q   = ws;
    float* k   = ws + QKV;
    float* v   = ws + 2 * QKV;
    float* ctx = ws + 3 * QKV;  // B*S*40 floats

    k_ln_qkv<<<512, 256, 0, stream>>>(x, g1, be1, Wq, bq, Wk, bk, Wv, bv, q, k, v);
    k_attn<<<512, 256, 0, stream>>>(q, k, v, ctx);
    k_out_ffn<<<512, 256, 0, stream>>>(ctx, x, Wo, bo, g2, bt2, W1, b1, W2, b2,
                                       (float*)d_out);
}